// Round 4
// baseline (2553.510 us; speedup 1.0000x reference)
//
#include <hip/hip_runtime.h>
#include <hip/hip_bf16.h>
#include <cstdint>
#include <cstddef>

#define T_   10
#define B_   128
#define CH_  512
#define N_   16
#define H_   16
#define HID_ 2048
#define TB_  (T_ * B_)       // 1280 (t,b) slabs
#define CN_  (CH_ * N_)      // 8192 elements per (t,b) slab

// B-source modes / epilogue modes for the fused GEMM+LIF
#define BM_F32    0   // fp32 activations (x)
#define BM_U8     1   // u8 spikes
#define BM_ADD    2   // fp32 x + u8 spike (x + s_proj), computed on the fly
#define BM_PACK   3   // u16 bit-packed spikes (bit n = token n)
#define EM_QKV    0   // scatter spikes to qs/ks/vs in scan layout
#define EM_U8     1   // plain (T,B,C,N) u8 spikes
#define EM_PACK   2   // ballot-packed u16 per (slab, row)
#define EM_OUT    3   // fp32 out = x + s_proj + spike

// ---------------------------------------------------------------------------
// Prep: fold BN (and optional conv bias) into weights, transpose to K-major.
// u = (dot + eb - mu) * inv + beta  =  dot' + bias,  At[k][o] = W[o][k]*inv
// ---------------------------------------------------------------------------
__global__ void fold_kernel(const float* __restrict__ W, const float* __restrict__ bnp,
                            const float* __restrict__ eb, int M, int K, int Mld, int o0,
                            float* __restrict__ At, float* __restrict__ bias) {
    int idx = blockIdx.x * 256 + threadIdx.x;
    if (idx >= M * K) return;
    int k = idx / M;
    int o = idx - k * M;
    float g  = bnp[o];
    float be = bnp[M + o];
    float mu = bnp[2 * M + o];
    float va = bnp[3 * M + o];
    float inv = g * (1.0f / sqrtf(va + 1e-5f));
    At[(size_t)k * Mld + o0 + o] = W[(size_t)o * K + k] * inv;
    if (k == 0) bias[o0 + o] = ((eb ? eb[o] : 0.0f) - mu) * inv + be;
}

// ---------------------------------------------------------------------------
// Fused GEMM + LIF. One block: 64 output rows x (10 t x 16 n) for one b.
// Thread micro-tile: 4 rows x 10 t, fixed token n. LIF over t is thread-local,
// so no fp32 pre-activation is ever materialized in HBM.
//   u[t][row][n] = sum_k At[k][row] * B[t,b][k][n] + bias[row]; spikes out.
// ---------------------------------------------------------------------------
template <int BM, int EM>
__global__ __launch_bounds__(256) void gemm_lif(
    const float* __restrict__ At, const float* __restrict__ bias,
    const float* __restrict__ Bf, const uint8_t* __restrict__ Bu,
    const uint16_t* __restrict__ Bp,
    uint8_t* __restrict__ O0, uint8_t* __restrict__ O1, uint8_t* __restrict__ O2,
    uint16_t* __restrict__ Op, float* __restrict__ Ob,
    const float* __restrict__ Xr, const uint8_t* __restrict__ Sr,
    int M, int K) {
    __shared__ float As[16][64];     // [k][m]
    __shared__ float Bs[16][192];    // [k][n*12 + t]  (pad 12 keeps float4 align)
    const int tid  = threadIdx.x;
    const int row0 = blockIdx.x * 64;
    const int b    = blockIdx.y;
    const int n    = tid & 15;
    const int rg   = tid >> 4;       // 0..15, rows rg*4..rg*4+3
    const int lka  = tid >> 4;       // A-loader k row
    const int lm4  = (tid & 15) * 4; // A-loader col

    float acc[10][4] = {};

    for (int k0 = 0; k0 < K; k0 += 16) {
        __syncthreads();
        // --- stage A tile: 16k x 64m ---
        *(float4*)&As[lka][lm4] =
            *(const float4*)&At[(size_t)(k0 + lka) * M + row0 + lm4];
        // --- stage B tile: 16k x (10t x 16n) ---
        if constexpr (BM == BM_PACK) {
            if (tid < 160) {
                int t = tid >> 4, k = tid & 15;
                unsigned w = Bp[(size_t)(t * B_ + b) * K + k0 + k];
#pragma unroll
                for (int j = 0; j < 16; ++j)
                    Bs[k][j * 12 + t] = (float)((w >> j) & 1u);
            }
        } else {
            for (int j = tid; j < 640; j += 256) {
                int tk = j >> 2;            // 0..159
                int t  = tk >> 4;           // 0..9
                int k  = tk & 15;           // 0..15
                int n4 = (j & 3) * 4;       // 0,4,8,12
                size_t off = ((size_t)(t * B_ + b) * K + (k0 + k)) * 16 + n4;
                float v0, v1, v2, v3;
                if constexpr (BM == BM_F32) {
                    float4 bv = *(const float4*)&Bf[off];
                    v0 = bv.x; v1 = bv.y; v2 = bv.z; v3 = bv.w;
                } else if constexpr (BM == BM_U8) {
                    uchar4 uv = *(const uchar4*)&Bu[off];
                    v0 = (float)uv.x; v1 = (float)uv.y; v2 = (float)uv.z; v3 = (float)uv.w;
                } else {  // BM_ADD: fp32 x + u8 spike
                    float4 bv = *(const float4*)&Bf[off];
                    uchar4 uv = *(const uchar4*)&Bu[off];
                    v0 = bv.x + (float)uv.x; v1 = bv.y + (float)uv.y;
                    v2 = bv.z + (float)uv.z; v3 = bv.w + (float)uv.w;
                }
                Bs[k][(n4 + 0) * 12 + t] = v0;
                Bs[k][(n4 + 1) * 12 + t] = v1;
                Bs[k][(n4 + 2) * 12 + t] = v2;
                Bs[k][(n4 + 3) * 12 + t] = v3;
            }
        }
        __syncthreads();
#pragma unroll
        for (int k = 0; k < 16; ++k) {
            float4 a  = *(float4*)&As[k][rg * 4];
            float4 b0 = *(float4*)&Bs[k][n * 12];
            float4 b1 = *(float4*)&Bs[k][n * 12 + 4];
            float2 b2 = *(float2*)&Bs[k][n * 12 + 8];
            float ar[4]  = {a.x, a.y, a.z, a.w};
            float bt[10] = {b0.x, b0.y, b0.z, b0.w, b1.x, b1.y, b1.z, b1.w, b2.x, b2.y};
#pragma unroll
            for (int t = 0; t < 10; ++t)
#pragma unroll
                for (int r = 0; r < 4; ++r)
                    acc[t][r] = fmaf(ar[r], bt[t], acc[t][r]);
        }
    }

    // --- epilogue: LIF over t per (row, n), emit spikes ---
#pragma unroll
    for (int r = 0; r < 4; ++r) {
        const int row = row0 + rg * 4 + r;
        const float bsv = bias[row];
        // QKV scatter coords (row-dependent only):
        //   flat c*16+n -> n_tok = c>>5, h = (c&31)>>1, d = ((c&1)<<4)|n
        int tsr = row >> 9;
        int c   = row & 511;
        int hh  = (c & 31) >> 1;
        int dd  = ((c & 1) << 4) | n;
        int nn  = c >> 5;
        uint8_t* qp = (tsr == 0) ? O0 : ((tsr == 1) ? O1 : O2);
        size_t qoff = (size_t)hh * 512 + dd * 16 + nn;
        float mem = 0.0f;
#pragma unroll
        for (int t = 0; t < 10; ++t) {
            float u = acc[t][r] + bsv;
            mem += (u - mem) * 0.5f;
            bool s = mem > 1.0f;
            if (s) mem = 0.0f;
            if constexpr (EM == EM_QKV) {
                qp[(size_t)(t * B_ + b) * 8192 + qoff] = (uint8_t)s;
            } else if constexpr (EM == EM_U8) {
                O0[(size_t)(t * B_ + b) * 8192 + (size_t)row * 16 + n] = (uint8_t)s;
            } else if constexpr (EM == EM_PACK) {
                unsigned long long mk = __ballot((int)s);
                if (n == 0)
                    Op[(size_t)(t * B_ + b) * 2048 + row] =
                        (uint16_t)(mk >> ((rg & 3) * 16));
            } else {  // EM_OUT: out = x + s_proj + spike, fp32
                size_t off = (size_t)(t * B_ + b) * 8192 + (size_t)row * 16 + n;
                Ob[off] = Xr[off] + (float)Sr[off] + (s ? 1.0f : 0.0f);
            }
        }
    }
}

// ---------------------------------------------------------------------------
// Temporal scan: one block per (b,h). t=0 plain attention from q0; t=1..9:
// conv1d(channels=N over spatial D) + LIF1 + mix + LIF2 + attention.
// attn_lif is fused (per-thread mem3 across the t loop) -> y1 spikes u8.
// LDS spike layout: element (token n, feature d) at [d*16 + n] == tid.
// ---------------------------------------------------------------------------
__global__ __launch_bounds__(512) void scan_kernel(
    const uint8_t* __restrict__ qs, const uint8_t* __restrict__ ks,
    const uint8_t* __restrict__ vs, const float* __restrict__ tiw,
    const float* __restrict__ tib, uint8_t* __restrict__ y1) {
    __shared__ float wl[1280];     // ti_w [o][i][k]
    __shared__ float tibl[16];
    __shared__ float qti[512];     // carry spikes [d*16+n]
    __shared__ float ktl[512];
    __shared__ float vtl[512];
    __shared__ float Al[256];      // A[n][m]
    const int tid = threadIdx.x;
    const int bh = blockIdx.x;
    const int b = bh >> 4;
    const int h = bh & 15;
    const int n = tid & 15;        // token
    const int d = tid >> 4;        // feature 0..31

    for (int i = tid; i < 1280; i += 512) wl[i] = tiw[i];
    if (tid < 16) tibl[tid] = tib[tid];

    size_t base0 = ((size_t)b * 16 + h) * 512 + tid;
    qti[tid] = (float)qs[base0];
    ktl[tid] = (float)ks[base0];
    vtl[tid] = (float)vs[base0];
    __syncthreads();

    float mem3 = 0.0f;
    // t = 0
    if (tid < 256) {
        int nn = tid & 15, mm = tid >> 4;
        float a = 0.0f;
#pragma unroll
        for (int ddx = 0; ddx < 32; ++ddx)
            a = fmaf(qti[ddx * 16 + nn], ktl[ddx * 16 + mm], a);
        Al[nn * 16 + mm] = a * 0.25f;
    }
    __syncthreads();
    {
        float o = 0.0f;
#pragma unroll
        for (int m = 0; m < 16; ++m)
            o = fmaf(Al[n * 16 + m], vtl[d * 16 + m], o);
        mem3 += (o - mem3) * 0.5f;
        bool s3 = mem3 > 1.0f;
        if (s3) mem3 = 0.0f;
        y1[(size_t)b * 8192 + (size_t)h * 512 + tid] = (uint8_t)s3;
    }

    float mem1 = 0.0f, mem2 = 0.0f;
    for (int t = 1; t < T_; ++t) {
        size_t base = ((size_t)(t * B_ + b) * 16 + h) * 512 + tid;
        float qb = (float)qs[base];
        float kb = (float)ks[base];
        float vb = (float)vs[base];
        // conv1d: out channel = n (token), spatial = d
        float c = tibl[n];
#pragma unroll
        for (int k = 0; k < 5; ++k) {
            int x = d + k - 2;
            if (x >= 0 && x < 32) {
#pragma unroll
                for (int i = 0; i < 16; ++i)
                    c = fmaf(wl[n * 80 + i * 5 + k], qti[x * 16 + i], c);
            }
        }
        mem1 += (c - mem1) * 0.5f;
        bool s1 = mem1 > 1.0f;
        if (s1) mem1 = 0.0f;
        float mix = 0.5f * (s1 ? 1.0f : 0.0f) + 0.5f * qb;
        mem2 += (mix - mem2) * 0.5f;
        bool s2 = mem2 > 1.0f;
        if (s2) mem2 = 0.0f;
        __syncthreads();               // conv/attn reads of prev LDS done
        qti[tid] = s2 ? 1.0f : 0.0f;
        ktl[tid] = kb;
        vtl[tid] = vb;
        __syncthreads();
        if (tid < 256) {
            int nn = tid & 15, mm = tid >> 4;
            float a = 0.0f;
#pragma unroll
            for (int ddx = 0; ddx < 32; ++ddx)
                a = fmaf(qti[ddx * 16 + nn], ktl[ddx * 16 + mm], a);
            Al[nn * 16 + mm] = a * 0.25f;
        }
        __syncthreads();
        float o = 0.0f;
#pragma unroll
        for (int m = 0; m < 16; ++m)
            o = fmaf(Al[n * 16 + m], vtl[d * 16 + m], o);
        mem3 += (o - mem3) * 0.5f;
        bool s3 = mem3 > 1.0f;
        if (s3) mem3 = 0.0f;
        y1[(size_t)(t * B_ + b) * 8192 + (size_t)h * 512 + tid] = (uint8_t)s3;
    }
}

// ---------------------------------------------------------------------------
extern "C" void kernel_launch(void* const* d_in, const int* in_sizes, int n_in,
                              void* d_out, int out_size, void* d_ws, size_t ws_size,
                              hipStream_t stream) {
    // Inputs are float32 per the reference's setup_inputs(); output float32.
    const float* x    = (const float*)d_in[0];
    const float* Wq   = (const float*)d_in[1];
    const float* Wk   = (const float*)d_in[2];
    const float* Wv   = (const float*)d_in[3];
    const float* Wp   = (const float*)d_in[4];
    const float* bnq  = (const float*)d_in[5];
    const float* bnk  = (const float*)d_in[6];
    const float* bnv  = (const float*)d_in[7];
    const float* bnpj = (const float*)d_in[8];
    const float* tiw  = (const float*)d_in[9];
    const float* tib  = (const float*)d_in[10];
    const float* W1   = (const float*)d_in[11];
    const float* b1   = (const float*)d_in[12];
    const float* bn1  = (const float*)d_in[13];
    const float* W2   = (const float*)d_in[14];
    const float* b2   = (const float*)d_in[15];
    const float* bn2  = (const float*)d_in[16];
    float* out = (float*)d_out;

    char* ws = (char*)d_ws;
    size_t cur = 0;
    auto alloc = [&](size_t bytes) -> void* {
        void* p = ws + cur;
        cur = (cur + bytes + 255) & ~(size_t)255;
        return p;
    };
    float*    At_qkv = (float*)alloc((size_t)512 * 1536 * 4);
    float*    bs_qkv = (float*)alloc(1536 * 4);
    float*    At_p   = (float*)alloc((size_t)512 * 512 * 4);
    float*    bs_p   = (float*)alloc(512 * 4);
    float*    At_1   = (float*)alloc((size_t)512 * 2048 * 4);
    float*    bs_1   = (float*)alloc(2048 * 4);
    float*    At_2   = (float*)alloc((size_t)2048 * 512 * 4);
    float*    bs_2   = (float*)alloc(512 * 4);
    uint8_t*  qs     = (uint8_t*)alloc((size_t)TB_ * 8192);
    uint8_t*  ksb    = (uint8_t*)alloc((size_t)TB_ * 8192);
    uint8_t*  vsb    = (uint8_t*)alloc((size_t)TB_ * 8192);
    uint8_t*  y1s    = (uint8_t*)alloc((size_t)TB_ * 8192);
    uint8_t*  sproj  = (uint8_t*)alloc((size_t)TB_ * 8192);
    uint16_t* hp     = (uint16_t*)alloc((size_t)TB_ * 2048 * 2);
    // total ~70 MB

    // --- prep (fold BN, transpose) ---
    fold_kernel<<<(512 * 512 + 255) / 256, 256, 0, stream>>>(Wq, bnq, nullptr, 512, 512, 1536, 0,    At_qkv, bs_qkv);
    fold_kernel<<<(512 * 512 + 255) / 256, 256, 0, stream>>>(Wk, bnk, nullptr, 512, 512, 1536, 512,  At_qkv, bs_qkv);
    fold_kernel<<<(512 * 512 + 255) / 256, 256, 0, stream>>>(Wv, bnv, nullptr, 512, 512, 1536, 1024, At_qkv, bs_qkv);
    fold_kernel<<<(512 * 512 + 255) / 256, 256, 0, stream>>>(Wp, bnpj, nullptr, 512, 512, 512, 0,    At_p, bs_p);
    fold_kernel<<<(2048 * 512 + 255) / 256, 256, 0, stream>>>(W1, bn1, b1, 2048, 512, 2048, 0,       At_1, bs_1);
    fold_kernel<<<(512 * 2048 + 255) / 256, 256, 0, stream>>>(W2, bn2, b2, 512, 2048, 512, 0,        At_2, bs_2);

    // --- SSA ---
    gemm_lif<BM_F32, EM_QKV><<<dim3(1536 / 64, B_), 256, 0, stream>>>(
        At_qkv, bs_qkv, x, nullptr, nullptr, qs, ksb, vsb, nullptr, nullptr,
        nullptr, nullptr, 1536, 512);
    scan_kernel<<<B_ * H_, 512, 0, stream>>>(qs, ksb, vsb, tiw, tib, y1s);
    gemm_lif<BM_U8, EM_U8><<<dim3(512 / 64, B_), 256, 0, stream>>>(
        At_p, bs_p, nullptr, y1s, nullptr, sproj, nullptr, nullptr, nullptr, nullptr,
        nullptr, nullptr, 512, 512);

    // --- MLP ---  (x2 = x + sproj recomputed on the fly, never materialized)
    gemm_lif<BM_ADD, EM_PACK><<<dim3(2048 / 64, B_), 256, 0, stream>>>(
        At_1, bs_1, x, sproj, nullptr, nullptr, nullptr, nullptr, hp, nullptr,
        nullptr, nullptr, 2048, 512);
    gemm_lif<BM_PACK, EM_OUT><<<dim3(512 / 64, B_), 256, 0, stream>>>(
        At_2, bs_2, nullptr, nullptr, hp, nullptr, nullptr, nullptr, nullptr, out,
        x, sproj, 512, 2048);
}

// Round 5
// 1072.522 us; speedup vs baseline: 2.3808x; 2.3808x over previous
//
#include <hip/hip_runtime.h>
#include <cstdint>
#include <cstddef>

#define T_   10
#define B_   128
#define CH_  512
#define N_   16
#define H_   16
#define HID_ 2048
#define TB_  (T_ * B_)       // 1280 (t,b) slabs

// B-source staging modes / epilogue modes
#define BS_XF32 0   // fp32 x, normal (T,B,C,N) layout -> split hi/lo on the fly
#define BS_XADD 1   // fp32 x + u8 sproj (normal layout) -> split hi/lo
#define BS_U8T  2   // u8 spikes in T-layout [slab*16+n][K] -> bf16 (exact)
#define EP_QKV  0   // scatter u8 spikes to qs/ks/vs in scan layout
#define EP_U8   1   // u8 spikes, normal (T,B,C,N) layout (sproj)
#define EP_HS   2   // u8 spikes, T-layout [slab*16+n][2048] (hsT)
#define EP_OUT  3   // fp32 out = x + sproj + spike

typedef __attribute__((ext_vector_type(8))) short bf16x8;
typedef __attribute__((ext_vector_type(4))) float f32x4;

__device__ __forceinline__ short f2b(float f) {      // fp32 -> bf16 bits, RNE
    uint32_t u = __float_as_uint(f);
    return (short)((u + 0x7FFFu + ((u >> 16) & 1u)) >> 16);
}
__device__ __forceinline__ float b2f(short s) {
    return __uint_as_float(((uint32_t)(uint16_t)s) << 16);
}

// ---------------------------------------------------------------------------
// Fold BN (+opt conv bias) into weights; emit bf16 hi/lo, [m][K] k-contig.
// ---------------------------------------------------------------------------
__global__ void fold2(const float* __restrict__ W, const float* __restrict__ bnp,
                      const float* __restrict__ eb, int M, int K, int o0,
                      short* __restrict__ Ah, short* __restrict__ Al,
                      float* __restrict__ bias) {
    int idx = blockIdx.x * 256 + threadIdx.x;
    if (idx >= M * K) return;
    int o = idx / K, k = idx - o * K;
    float g  = bnp[o];
    float be = bnp[M + o];
    float mu = bnp[2 * M + o];
    float va = bnp[3 * M + o];
    float inv = g * (1.0f / sqrtf(va + 1e-5f));
    float w = W[idx] * inv;
    short h = f2b(w);
    Ah[(size_t)(o0 + o) * K + k] = h;
    Al[(size_t)(o0 + o) * K + k] = f2b(w - b2f(h));
    if (k == 0) bias[o0 + o] = ((eb ? eb[o] : 0.0f) - mu) * inv + be;
}

// ---------------------------------------------------------------------------
// MFMA GEMM + fused LIF. Wave: R 16-row tiles x 16 tokens x all 10 t accs.
// A (bf16 hi/lo, [m][K]) read straight from global; B staged to LDS per
// 32-k chunk in frag layout [t][n][k] (pitch 40). Split-precision:
//   spikes (BS_U8T):  2 passes  Ah*B + Al*B          (exact)
//   fp32   (else):    3 passes  Ah*Bh + Al*Bh + Ah*Bl (err ~2^-18)
// ---------------------------------------------------------------------------
template <int R, int BS, int EPI>
__global__ __launch_bounds__(256, 2) void gemm_mfma(
    const short* __restrict__ Ah, const short* __restrict__ Al,
    const float* __restrict__ bias,
    const float* __restrict__ Bx, const uint8_t* __restrict__ Bu,
    uint8_t* __restrict__ O0, uint8_t* __restrict__ O1, uint8_t* __restrict__ O2,
    float* __restrict__ Oout, const float* __restrict__ Xr,
    const uint8_t* __restrict__ Sr, int K) {
    constexpr int NP = (BS == BS_U8T) ? 2 : 3;
    __shared__ __align__(16) short Bs[(NP == 3 ? 2 : 1) * 6400];  // [t][n][k], pitch 40
    short* BsH = Bs;
    short* BsL = Bs + 6400;
    const int tid  = threadIdx.x;
    const int lane = tid & 63;
    const int wv   = tid >> 6;
    const int b    = blockIdx.y;
    const int l15  = lane & 15;
    const int q    = lane >> 4;
    const int row0 = blockIdx.x * (R * 64) + wv * (R * 16);

    f32x4 acc[R][10];
#pragma unroll
    for (int r = 0; r < R; ++r)
#pragma unroll
        for (int t = 0; t < 10; ++t) acc[r][t] = 0.0f;

    for (int k0 = 0; k0 < K; k0 += 32) {
        __syncthreads();
        // ---- stage B chunk: 10t x 16n x 32k ----
        if constexpr (BS == BS_U8T) {
            for (int idx = tid; idx < 640; idx += 256) {
                int qu = idx & 3, n = (idx >> 2) & 15, t = idx >> 6;
                size_t g = ((size_t)(t * B_ + b) * 16 + n) * K + k0 + qu * 8;
                uint2 w = *(const uint2*)&Bu[g];
                union { short s[8]; uint4 v; } hb;
#pragma unroll
                for (int j = 0; j < 4; ++j) {
                    hb.s[j]     = ((w.x >> (8 * j)) & 255u) ? (short)0x3F80 : (short)0;
                    hb.s[4 + j] = ((w.y >> (8 * j)) & 255u) ? (short)0x3F80 : (short)0;
                }
                *(uint4*)&BsH[(t * 16 + n) * 40 + qu * 8] = hb.v;
            }
        } else {
            for (int idx = tid; idx < 640; idx += 256) {
                int qu = idx & 3, n = (idx >> 2) & 15, t = idx >> 6;
                size_t base = (size_t)(t * B_ + b) * 8192 + (size_t)(k0 + qu * 8) * 16 + n;
                union { short s[8]; uint4 v; } hb, lb;
#pragma unroll
                for (int j = 0; j < 8; ++j) {
                    float v = Bx[base + j * 16];
                    if constexpr (BS == BS_XADD) v += (float)Sr[base + j * 16];
                    short h = f2b(v);
                    hb.s[j] = h;
                    lb.s[j] = f2b(v - b2f(h));
                }
                *(uint4*)&BsH[(t * 16 + n) * 40 + qu * 8] = hb.v;
                *(uint4*)&BsL[(t * 16 + n) * 40 + qu * 8] = lb.v;
            }
        }
        __syncthreads();
        // ---- A fragments from global (L2-resident) ----
        bf16x8 ah[R], al[R];
#pragma unroll
        for (int r = 0; r < R; ++r) {
            size_t ga = (size_t)(row0 + r * 16 + l15) * K + k0 + q * 8;
            ah[r] = *(const bf16x8*)&Ah[ga];
            al[r] = *(const bf16x8*)&Al[ga];
        }
        // ---- MFMA over 10 t ----
#pragma unroll
        for (int t = 0; t < 10; ++t) {
            bf16x8 bh = *(const bf16x8*)&BsH[(t * 16 + l15) * 40 + q * 8];
            bf16x8 bl;
            if constexpr (NP == 3) bl = *(const bf16x8*)&BsL[(t * 16 + l15) * 40 + q * 8];
#pragma unroll
            for (int r = 0; r < R; ++r) {
                acc[r][t] = __builtin_amdgcn_mfma_f32_16x16x32_bf16(ah[r], bh, acc[r][t], 0, 0, 0);
                acc[r][t] = __builtin_amdgcn_mfma_f32_16x16x32_bf16(al[r], bh, acc[r][t], 0, 0, 0);
                if constexpr (NP == 3)
                    acc[r][t] = __builtin_amdgcn_mfma_f32_16x16x32_bf16(ah[r], bl, acc[r][t], 0, 0, 0);
            }
        }
    }

    // ---- epilogue: lane holds (row = q*4+reg, tok = l15) x all 10 t ----
    const int tok = l15;
#pragma unroll
    for (int r = 0; r < R; ++r) {
#pragma unroll
        for (int reg = 0; reg < 4; ++reg) {
            const int row = row0 + r * 16 + q * 4 + reg;
            const float bsv = bias[row];
            // QKV scatter coords (row/tok dependent)
            int tsr = row >> 9;
            int c   = row & 511;
            int hh  = (c & 31) >> 1;
            int dd  = ((c & 1) << 4) | tok;
            int nn  = c >> 5;
            uint8_t* qp = (tsr == 0) ? O0 : ((tsr == 1) ? O1 : O2);
            size_t qoff = (size_t)hh * 512 + dd * 16 + nn;
            float mem = 0.0f;
#pragma unroll
            for (int t = 0; t < 10; ++t) {
                float u = acc[r][t][reg] + bsv;
                mem += (u - mem) * 0.5f;
                bool s = mem > 1.0f;
                if (s) mem = 0.0f;
                if constexpr (EPI == EP_QKV) {
                    qp[(size_t)(t * B_ + b) * 8192 + qoff] = (uint8_t)s;
                } else if constexpr (EPI == EP_U8) {
                    O0[(size_t)(t * B_ + b) * 8192 + (size_t)row * 16 + tok] = (uint8_t)s;
                } else if constexpr (EPI == EP_HS) {
                    O0[((size_t)(t * B_ + b) * 16 + tok) * 2048 + row] = (uint8_t)s;
                } else {  // EP_OUT
                    size_t off = (size_t)(t * B_ + b) * 8192 + (size_t)row * 16 + tok;
                    Oout[off] = Xr[off] + (float)Sr[off] + (s ? 1.0f : 0.0f);
                }
            }
        }
    }
}

// ---------------------------------------------------------------------------
// Temporal scan (as round 4) + attn_lif fused; y1 emitted as u8 T-layout
// [slab*16 + n][c] via a small LDS transpose tile.
// ---------------------------------------------------------------------------
__global__ __launch_bounds__(512) void scan_kernel(
    const uint8_t* __restrict__ qs, const uint8_t* __restrict__ ks,
    const uint8_t* __restrict__ vs, const float* __restrict__ tiw,
    const float* __restrict__ tib, uint8_t* __restrict__ y1T) {
    __shared__ float wl[1280];
    __shared__ float tibl[16];
    __shared__ float qti[512];
    __shared__ float ktl[512];
    __shared__ float vtl[512];
    __shared__ float Al[256];
    __shared__ unsigned char ytile[512];   // [n][d]
    const int tid = threadIdx.x;
    const int bh = blockIdx.x;
    const int b = bh >> 4;
    const int h = bh & 15;
    const int n = tid & 15;
    const int d = tid >> 4;

    for (int i = tid; i < 1280; i += 512) wl[i] = tiw[i];
    if (tid < 16) tibl[tid] = tib[tid];

    size_t base0 = ((size_t)b * 16 + h) * 512 + tid;
    qti[tid] = (float)qs[base0];
    ktl[tid] = (float)ks[base0];
    vtl[tid] = (float)vs[base0];
    __syncthreads();

    float mem3 = 0.0f;
    // t = 0
    if (tid < 256) {
        int nn = tid & 15, mm = tid >> 4;
        float a = 0.0f;
#pragma unroll
        for (int ddx = 0; ddx < 32; ++ddx)
            a = fmaf(qti[ddx * 16 + nn], ktl[ddx * 16 + mm], a);
        Al[nn * 16 + mm] = a * 0.25f;
    }
    __syncthreads();
    {
        float o = 0.0f;
#pragma unroll
        for (int m = 0; m < 16; ++m)
            o = fmaf(Al[n * 16 + m], vtl[d * 16 + m], o);
        mem3 += (o - mem3) * 0.5f;
        bool s3 = mem3 > 1.0f;
        if (s3) mem3 = 0.0f;
        ytile[n * 32 + d] = (uint8_t)s3;
    }

    float mem1 = 0.0f, mem2 = 0.0f;
    for (int t = 1; t < T_; ++t) {
        size_t base = ((size_t)(t * B_ + b) * 16 + h) * 512 + tid;
        float qb = (float)qs[base];
        float kb = (float)ks[base];
        float vb = (float)vs[base];
        float c = tibl[n];
#pragma unroll
        for (int k = 0; k < 5; ++k) {
            int x = d + k - 2;
            if (x >= 0 && x < 32) {
#pragma unroll
                for (int i = 0; i < 16; ++i)
                    c = fmaf(wl[n * 80 + i * 5 + k], qti[x * 16 + i], c);
            }
        }
        mem1 += (c - mem1) * 0.5f;
        bool s1 = mem1 > 1.0f;
        if (s1) mem1 = 0.0f;
        float mix = 0.5f * (s1 ? 1.0f : 0.0f) + 0.5f * qb;
        mem2 += (mix - mem2) * 0.5f;
        bool s2 = mem2 > 1.0f;
        if (s2) mem2 = 0.0f;
        __syncthreads();
        // flush ytile for t-1 (coalesced T-layout write)
        if (tid < 256) {
            int nn2 = tid >> 4, d0 = (tid & 15) * 2;
            *(uchar2*)&y1T[((size_t)((t - 1) * B_ + b) * 16 + nn2) * 512 + h * 32 + d0] =
                *(uchar2*)&ytile[nn2 * 32 + d0];
        }
        qti[tid] = s2 ? 1.0f : 0.0f;
        ktl[tid] = kb;
        vtl[tid] = vb;
        __syncthreads();
        if (tid < 256) {
            int nn = tid & 15, mm = tid >> 4;
            float a = 0.0f;
#pragma unroll
            for (int ddx = 0; ddx < 32; ++ddx)
                a = fmaf(qti[ddx * 16 + nn], ktl[ddx * 16 + mm], a);
            Al[nn * 16 + mm] = a * 0.25f;
        }
        __syncthreads();
        float o = 0.0f;
#pragma unroll
        for (int m = 0; m < 16; ++m)
            o = fmaf(Al[n * 16 + m], vtl[d * 16 + m], o);
        mem3 += (o - mem3) * 0.5f;
        bool s3 = mem3 > 1.0f;
        if (s3) mem3 = 0.0f;
        ytile[n * 32 + d] = (uint8_t)s3;
    }
    __syncthreads();
    if (tid < 256) {
        int nn2 = tid >> 4, d0 = (tid & 15) * 2;
        *(uchar2*)&y1T[((size_t)(9 * B_ + b) * 16 + nn2) * 512 + h * 32 + d0] =
            *(uchar2*)&ytile[nn2 * 32 + d0];
    }
}

// ---------------------------------------------------------------------------
extern "C" void kernel_launch(void* const* d_in, const int* in_sizes, int n_in,
                              void* d_out, int out_size, void* d_ws, size_t ws_size,
                              hipStream_t stream) {
    const float* x    = (const float*)d_in[0];
    const float* Wq   = (const float*)d_in[1];
    const float* Wk   = (const float*)d_in[2];
    const float* Wv   = (const float*)d_in[3];
    const float* Wp   = (const float*)d_in[4];
    const float* bnq  = (const float*)d_in[5];
    const float* bnk  = (const float*)d_in[6];
    const float* bnv  = (const float*)d_in[7];
    const float* bnpj = (const float*)d_in[8];
    const float* tiw  = (const float*)d_in[9];
    const float* tib  = (const float*)d_in[10];
    const float* W1   = (const float*)d_in[11];
    const float* b1   = (const float*)d_in[12];
    const float* bn1  = (const float*)d_in[13];
    const float* W2   = (const float*)d_in[14];
    const float* b2   = (const float*)d_in[15];
    const float* bn2  = (const float*)d_in[16];
    float* out = (float*)d_out;

    char* ws = (char*)d_ws;
    size_t cur = 0;
    auto alloc = [&](size_t bytes) -> void* {
        void* p = ws + cur;
        cur = (cur + bytes + 255) & ~(size_t)255;
        return p;
    };
    const size_t SL = (size_t)TB_ * 8192;   // 10.5M
    uint8_t* hsT   = (uint8_t*)alloc(4 * SL);  // [slab*16+n][2048]; overlays qkv spikes
    uint8_t* qsb   = hsT;                      // scan-layout spikes (dead before hsT written)
    uint8_t* ksb   = hsT + SL;
    uint8_t* vsb   = hsT + 2 * SL;
    uint8_t* y1T   = hsT + 3 * SL;             // T-layout spikes (dead before hsT written)
    uint8_t* sproj = (uint8_t*)alloc(SL);
    short* Ah_qkv = (short*)alloc((size_t)1536 * 512 * 2);
    short* Al_qkv = (short*)alloc((size_t)1536 * 512 * 2);
    short* Ah_p   = (short*)alloc((size_t)512 * 512 * 2);
    short* Al_p   = (short*)alloc((size_t)512 * 512 * 2);
    short* Ah_1   = (short*)alloc((size_t)2048 * 512 * 2);
    short* Al_1   = (short*)alloc((size_t)2048 * 512 * 2);
    short* Ah_2   = (short*)alloc((size_t)512 * 2048 * 2);
    short* Al_2   = (short*)alloc((size_t)512 * 2048 * 2);
    float* bs_qkv = (float*)alloc(1536 * 4);
    float* bs_p   = (float*)alloc(512 * 4);
    float* bs_1   = (float*)alloc(2048 * 4);
    float* bs_2   = (float*)alloc(512 * 4);
    // total ~65 MB

    // --- prep: fold BN, split bf16 hi/lo, [m][K] ---
    fold2<<<1024, 256, 0, stream>>>(Wq, bnq, nullptr, 512, 512, 0,    Ah_qkv, Al_qkv, bs_qkv);
    fold2<<<1024, 256, 0, stream>>>(Wk, bnk, nullptr, 512, 512, 512,  Ah_qkv, Al_qkv, bs_qkv);
    fold2<<<1024, 256, 0, stream>>>(Wv, bnv, nullptr, 512, 512, 1024, Ah_qkv, Al_qkv, bs_qkv);
    fold2<<<1024, 256, 0, stream>>>(Wp, bnpj, nullptr, 512, 512, 0,   Ah_p, Al_p, bs_p);
    fold2<<<4096, 256, 0, stream>>>(W1, bn1, b1, 2048, 512, 0,        Ah_1, Al_1, bs_1);
    fold2<<<4096, 256, 0, stream>>>(W2, bn2, b2, 512, 2048, 0,        Ah_2, Al_2, bs_2);

    // --- SSA ---
    gemm_mfma<4, BS_XF32, EP_QKV><<<dim3(6, B_), 256, 0, stream>>>(
        Ah_qkv, Al_qkv, bs_qkv, x, nullptr, qsb, ksb, vsb,
        nullptr, nullptr, nullptr, 512);
    scan_kernel<<<B_ * H_, 512, 0, stream>>>(qsb, ksb, vsb, tiw, tib, y1T);
    gemm_mfma<2, BS_U8T, EP_U8><<<dim3(4, B_), 256, 0, stream>>>(
        Ah_p, Al_p, bs_p, nullptr, y1T, sproj, nullptr, nullptr,
        nullptr, nullptr, nullptr, 512);

    // --- MLP ---  (x2 = x + sproj formed on the fly in staging)
    gemm_mfma<4, BS_XADD, EP_HS><<<dim3(8, B_), 256, 0, stream>>>(
        Ah_1, Al_1, bs_1, x, nullptr, hsT, nullptr, nullptr,
        nullptr, nullptr, sproj, 512);
    gemm_mfma<2, BS_U8T, EP_OUT><<<dim3(4, B_), 256, 0, stream>>>(
        Ah_2, Al_2, bs_2, nullptr, hsT, nullptr, nullptr, nullptr,
        out, x, sproj, 2048);
}

// Round 6
// 886.914 us; speedup vs baseline: 2.8791x; 1.2093x over previous
//
#include <hip/hip_runtime.h>
#include <cstdint>
#include <cstddef>

#define T_   10
#define B_   128
#define CH_  512
#define N_   16
#define H_   16
#define HID_ 2048
#define TB_  (T_ * B_)       // 1280 (t,b) slabs

// B-source staging modes / epilogue modes
#define BS_XF32 0   // fp32 x, normal (T,B,C,N) layout -> split hi/lo on the fly
#define BS_XADD 1   // fp32 x + u8 sproj (normal layout) -> split hi/lo
#define BS_U8T  2   // u8 spikes in T-layout [slab*16+n][K] -> bf16 (exact)
#define EP_QKV  0   // scatter u8 spikes to qs/ks/vs in scan layout
#define EP_U8   1   // u8 spikes, normal (T,B,C,N) layout (sproj)
#define EP_HS   2   // u8 spikes, T-layout [slab*16+n][2048] (hsT)
#define EP_OUT  3   // fp32 out = x + sproj + spike

typedef __attribute__((ext_vector_type(8))) short bf16x8;
typedef __attribute__((ext_vector_type(4))) float f32x4;

__device__ __forceinline__ short f2b(float f) {      // fp32 -> bf16 bits, RNE
    uint32_t u = __float_as_uint(f);
    return (short)((u + 0x7FFFu + ((u >> 16) & 1u)) >> 16);
}
__device__ __forceinline__ float b2f(short s) {
    return __uint_as_float(((uint32_t)(uint16_t)s) << 16);
}

// ---------------------------------------------------------------------------
// Fold BN (+opt conv bias) into weights; emit bf16 hi/lo, [m][K] k-contig.
// ---------------------------------------------------------------------------
__global__ void fold2(const float* __restrict__ W, const float* __restrict__ bnp,
                      const float* __restrict__ eb, int M, int K, int o0,
                      short* __restrict__ Ah, short* __restrict__ Al,
                      float* __restrict__ bias) {
    int idx = blockIdx.x * 256 + threadIdx.x;
    if (idx >= M * K) return;
    int o = idx / K, k = idx - o * K;
    float g  = bnp[o];
    float be = bnp[M + o];
    float mu = bnp[2 * M + o];
    float va = bnp[3 * M + o];
    float inv = g * (1.0f / sqrtf(va + 1e-5f));
    float w = W[idx] * inv;
    short h = f2b(w);
    Ah[(size_t)(o0 + o) * K + k] = h;
    Al[(size_t)(o0 + o) * K + k] = f2b(w - b2f(h));
    if (k == 0) bias[o0 + o] = ((eb ? eb[o] : 0.0f) - mu) * inv + be;
}

// ---------------------------------------------------------------------------
// MFMA GEMM + fused LIF (unchanged from round 5, known-good).
// ---------------------------------------------------------------------------
template <int R, int BS, int EPI>
__global__ __launch_bounds__(256, 2) void gemm_mfma(
    const short* __restrict__ Ah, const short* __restrict__ Al,
    const float* __restrict__ bias,
    const float* __restrict__ Bx, const uint8_t* __restrict__ Bu,
    uint8_t* __restrict__ O0, uint8_t* __restrict__ O1, uint8_t* __restrict__ O2,
    float* __restrict__ Oout, const float* __restrict__ Xr,
    const uint8_t* __restrict__ Sr, int K) {
    constexpr int NP = (BS == BS_U8T) ? 2 : 3;
    __shared__ __align__(16) short Bs[(NP == 3 ? 2 : 1) * 6400];  // [t][n][k], pitch 40
    short* BsH = Bs;
    short* BsL = Bs + 6400;
    const int tid  = threadIdx.x;
    const int lane = tid & 63;
    const int wv   = tid >> 6;
    const int b    = blockIdx.y;
    const int l15  = lane & 15;
    const int q    = lane >> 4;
    const int row0 = blockIdx.x * (R * 64) + wv * (R * 16);

    f32x4 acc[R][10];
#pragma unroll
    for (int r = 0; r < R; ++r)
#pragma unroll
        for (int t = 0; t < 10; ++t) acc[r][t] = 0.0f;

    for (int k0 = 0; k0 < K; k0 += 32) {
        __syncthreads();
        // ---- stage B chunk: 10t x 16n x 32k ----
        if constexpr (BS == BS_U8T) {
            for (int idx = tid; idx < 640; idx += 256) {
                int qu = idx & 3, n = (idx >> 2) & 15, t = idx >> 6;
                size_t g = ((size_t)(t * B_ + b) * 16 + n) * K + k0 + qu * 8;
                uint2 w = *(const uint2*)&Bu[g];
                union { short s[8]; uint4 v; } hb;
#pragma unroll
                for (int j = 0; j < 4; ++j) {
                    hb.s[j]     = ((w.x >> (8 * j)) & 255u) ? (short)0x3F80 : (short)0;
                    hb.s[4 + j] = ((w.y >> (8 * j)) & 255u) ? (short)0x3F80 : (short)0;
                }
                *(uint4*)&BsH[(t * 16 + n) * 40 + qu * 8] = hb.v;
            }
        } else {
            for (int idx = tid; idx < 640; idx += 256) {
                int qu = idx & 3, n = (idx >> 2) & 15, t = idx >> 6;
                size_t base = (size_t)(t * B_ + b) * 8192 + (size_t)(k0 + qu * 8) * 16 + n;
                union { short s[8]; uint4 v; } hb, lb;
#pragma unroll
                for (int j = 0; j < 8; ++j) {
                    float v = Bx[base + j * 16];
                    if constexpr (BS == BS_XADD) v += (float)Sr[base + j * 16];
                    short h = f2b(v);
                    hb.s[j] = h;
                    lb.s[j] = f2b(v - b2f(h));
                }
                *(uint4*)&BsH[(t * 16 + n) * 40 + qu * 8] = hb.v;
                *(uint4*)&BsL[(t * 16 + n) * 40 + qu * 8] = lb.v;
            }
        }
        __syncthreads();
        // ---- A fragments from global (L2-resident) ----
        bf16x8 ah[R], al[R];
#pragma unroll
        for (int r = 0; r < R; ++r) {
            size_t ga = (size_t)(row0 + r * 16 + l15) * K + k0 + q * 8;
            ah[r] = *(const bf16x8*)&Ah[ga];
            al[r] = *(const bf16x8*)&Al[ga];
        }
        // ---- MFMA over 10 t ----
#pragma unroll
        for (int t = 0; t < 10; ++t) {
            bf16x8 bh = *(const bf16x8*)&BsH[(t * 16 + l15) * 40 + q * 8];
            bf16x8 bl;
            if constexpr (NP == 3) bl = *(const bf16x8*)&BsL[(t * 16 + l15) * 40 + q * 8];
#pragma unroll
            for (int r = 0; r < R; ++r) {
                acc[r][t] = __builtin_amdgcn_mfma_f32_16x16x32_bf16(ah[r], bh, acc[r][t], 0, 0, 0);
                acc[r][t] = __builtin_amdgcn_mfma_f32_16x16x32_bf16(al[r], bh, acc[r][t], 0, 0, 0);
                if constexpr (NP == 3)
                    acc[r][t] = __builtin_amdgcn_mfma_f32_16x16x32_bf16(ah[r], bl, acc[r][t], 0, 0, 0);
            }
        }
    }

    // ---- epilogue: lane holds (row = q*4+reg, tok = l15) x all 10 t ----
    const int tok = l15;
#pragma unroll
    for (int r = 0; r < R; ++r) {
#pragma unroll
        for (int reg = 0; reg < 4; ++reg) {
            const int row = row0 + r * 16 + q * 4 + reg;
            const float bsv = bias[row];
            int tsr = row >> 9;
            int c   = row & 511;
            int hh  = (c & 31) >> 1;
            int dd  = ((c & 1) << 4) | tok;
            int nn  = c >> 5;
            uint8_t* qp = (tsr == 0) ? O0 : ((tsr == 1) ? O1 : O2);
            size_t qoff = (size_t)hh * 512 + dd * 16 + nn;
            float mem = 0.0f;
#pragma unroll
            for (int t = 0; t < 10; ++t) {
                float u = acc[r][t][reg] + bsv;
                mem += (u - mem) * 0.5f;
                bool s = mem > 1.0f;
                if (s) mem = 0.0f;
                if constexpr (EPI == EP_QKV) {
                    qp[(size_t)(t * B_ + b) * 8192 + qoff] = (uint8_t)s;
                } else if constexpr (EPI == EP_U8) {
                    O0[(size_t)(t * B_ + b) * 8192 + (size_t)row * 16 + tok] = (uint8_t)s;
                } else if constexpr (EPI == EP_HS) {
                    O0[((size_t)(t * B_ + b) * 16 + tok) * 2048 + row] = (uint8_t)s;
                } else {  // EP_OUT
                    size_t off = (size_t)(t * B_ + b) * 8192 + (size_t)row * 16 + tok;
                    Oout[off] = Xr[off] + (float)Sr[off] + (s ? 1.0f : 0.0f);
                }
            }
        }
    }
}

// ---------------------------------------------------------------------------
// Wave-synchronous temporal scan: ONE WAVE per (b,h), zero barriers.
// Lane owns (token n = lane&15, features d = dg*8+dd, dg = lane>>4, dd<8).
// ti_w held in registers (80/lane, fixed n). LDS rows padded to 20 floats;
// conv carry qS has a 2-row zero halo (physical row = d + 2) -> no masking.
// LIF1/2/3 states in registers. y1 emitted u8 T-layout [slab*16+n][c].
// ---------------------------------------------------------------------------
__global__ __launch_bounds__(64, 2) void scan_kernel(
    const uint8_t* __restrict__ qs, const uint8_t* __restrict__ ks,
    const uint8_t* __restrict__ vs, const float* __restrict__ tiw,
    const float* __restrict__ tib, uint8_t* __restrict__ y1T) {
    __shared__ float qS[36 * 20];   // [d+2][n] spike carry, halo rows 0,1,34,35 = 0
    __shared__ float kS[32 * 20];   // [d][m]
    __shared__ float vS[32 * 20];   // [d][m]
    __shared__ float qbS[32 * 20];  // [d][n] current-t q spikes
    __shared__ float A[16 * 17];    // [n][m]
    const int l  = threadIdx.x;
    const int bh = blockIdx.x;
    const int b  = bh >> 4, h = bh & 15;
    const int n  = l & 15, dg = l >> 4;

    // ti_w into registers: wreg[i*5+k] = tiw[n*80 + i*5 + k]
    float wreg[80];
#pragma unroll
    for (int j = 0; j < 80; ++j) wreg[j] = tiw[n * 80 + j];
    const float tibr = tib[n];

    // zero the qS halo rows (0,1 and 34,35)
    if (l < 40) { qS[l] = 0.0f; qS[680 + l] = 0.0f; }

    // ---- t = 0 staging: q0 -> qS (carry), k0/v0 -> kS/vS ----
    {
        size_t base = (size_t)b * 8192 + (size_t)h * 512;
        unsigned long long qw = *(const unsigned long long*)&qs[base + l * 8];
        unsigned long long kw = *(const unsigned long long*)&ks[base + l * 8];
        unsigned long long vw = *(const unsigned long long*)&vs[base + l * 8];
#pragma unroll
        for (int j = 0; j < 8; ++j) {
            int f = l * 8 + j, d = f >> 4, m = f & 15;
            qS[(d + 2) * 20 + m] = (float)((qw >> (8 * j)) & 255);
            kS[d * 20 + m]       = (float)((kw >> (8 * j)) & 255);
            vS[d * 20 + m]       = (float)((vw >> (8 * j)) & 255);
        }
    }

    float mem1[8] = {}, mem2[8] = {}, mem3[8] = {};

    // ---- attention + attn_lif, shared by t=0 and t>=1 ----
    auto attn_step = [&](int t) {
        // QK^T: lane computes A[n][dg*4 + jj]
        float dots[4] = {0.0f, 0.0f, 0.0f, 0.0f};
#pragma unroll
        for (int d = 0; d < 32; ++d) {
            float qv = qS[(d + 2) * 20 + n];
#pragma unroll
            for (int jj = 0; jj < 4; ++jj)
                dots[jj] = fmaf(qv, kS[d * 20 + dg * 4 + jj], dots[jj]);
        }
#pragma unroll
        for (int jj = 0; jj < 4; ++jj) A[n * 17 + dg * 4 + jj] = dots[jj] * 0.25f;
        // PV: lane's 8 outputs (n, d = dg*8+dd)
        float o[8] = {};
#pragma unroll
        for (int m = 0; m < 16; ++m) {
            float av = A[n * 17 + m];
#pragma unroll
            for (int dd = 0; dd < 8; ++dd)
                o[dd] = fmaf(av, vS[(dg * 8 + dd) * 20 + m], o[dd]);
        }
        // attn_lif
        unsigned long long yw = 0;
#pragma unroll
        for (int dd = 0; dd < 8; ++dd) {
            mem3[dd] += (o[dd] - mem3[dd]) * 0.5f;
            bool s3 = mem3[dd] > 1.0f;
            if (s3) mem3[dd] = 0.0f;
            yw |= ((unsigned long long)(s3 ? 1u : 0u)) << (8 * dd);
        }
        *(unsigned long long*)
            &y1T[((size_t)(t * B_ + b) * 16 + n) * 512 + h * 32 + dg * 8] = yw;
    };

    attn_step(0);

    for (int t = 1; t < T_; ++t) {
        // ---- stage current k, v, q ----
        size_t base = (size_t)(t * B_ + b) * 8192 + (size_t)h * 512;
        unsigned long long qw = *(const unsigned long long*)&qs[base + l * 8];
        unsigned long long kw = *(const unsigned long long*)&ks[base + l * 8];
        unsigned long long vw = *(const unsigned long long*)&vs[base + l * 8];
#pragma unroll
        for (int j = 0; j < 8; ++j) {
            int f = l * 8 + j, d = f >> 4, m = f & 15;
            qbS[d * 20 + m] = (float)((qw >> (8 * j)) & 255);
            kS[d * 20 + m]  = (float)((kw >> (8 * j)) & 255);
            vS[d * 20 + m]  = (float)((vw >> (8 * j)) & 255);
        }
        // ---- conv1d over carry qS: c[n][d], d = dg*8 + dd ----
        float c[8];
#pragma unroll
        for (int dd = 0; dd < 8; ++dd) c[dd] = tibr;
#pragma unroll
        for (int x = 0; x < 12; ++x) {
            // physical row dg*8 + x  (= logical d+k-2 shifted by halo +2)
            const float* rp = &qS[(dg * 8 + x) * 20];
            float qrow[16];
            *(float4*)&qrow[0]  = *(const float4*)&rp[0];
            *(float4*)&qrow[4]  = *(const float4*)&rp[4];
            *(float4*)&qrow[8]  = *(const float4*)&rp[8];
            *(float4*)&qrow[12] = *(const float4*)&rp[12];
            const int kmin = (x > 7) ? (x - 7) : 0;
            const int kmax = (x < 4) ? x : 4;
#pragma unroll
            for (int i = 0; i < 16; ++i)
#pragma unroll 5
                for (int k = kmin; k <= kmax; ++k)
                    c[x - k] = fmaf(wreg[i * 5 + k], qrow[i], c[x - k]);
        }
        // ---- LIF1 -> mix -> LIF2 -> new carry spikes ----
#pragma unroll
        for (int dd = 0; dd < 8; ++dd) {
            mem1[dd] += (c[dd] - mem1[dd]) * 0.5f;
            bool s1 = mem1[dd] > 1.0f;
            if (s1) mem1[dd] = 0.0f;
            float qb = qbS[(dg * 8 + dd) * 20 + n];
            float mix = 0.5f * (s1 ? 1.0f : 0.0f) + 0.5f * qb;
            mem2[dd] += (mix - mem2[dd]) * 0.5f;
            bool s2 = mem2[dd] > 1.0f;
            if (s2) mem2[dd] = 0.0f;
            qS[(dg * 8 + dd + 2) * 20 + n] = s2 ? 1.0f : 0.0f;
        }
        attn_step(t);
    }
}

// ---------------------------------------------------------------------------
extern "C" void kernel_launch(void* const* d_in, const int* in_sizes, int n_in,
                              void* d_out, int out_size, void* d_ws, size_t ws_size,
                              hipStream_t stream) {
    const float* x    = (const float*)d_in[0];
    const float* Wq   = (const float*)d_in[1];
    const float* Wk   = (const float*)d_in[2];
    const float* Wv   = (const float*)d_in[3];
    const float* Wp   = (const float*)d_in[4];
    const float* bnq  = (const float*)d_in[5];
    const float* bnk  = (const float*)d_in[6];
    const float* bnv  = (const float*)d_in[7];
    const float* bnpj = (const float*)d_in[8];
    const float* tiw  = (const float*)d_in[9];
    const float* tib  = (const float*)d_in[10];
    const float* W1   = (const float*)d_in[11];
    const float* b1   = (const float*)d_in[12];
    const float* bn1  = (const float*)d_in[13];
    const float* W2   = (const float*)d_in[14];
    const float* b2   = (const float*)d_in[15];
    const float* bn2  = (const float*)d_in[16];
    float* out = (float*)d_out;

    char* ws = (char*)d_ws;
    size_t cur = 0;
    auto alloc = [&](size_t bytes) -> void* {
        void* p = ws + cur;
        cur = (cur + bytes + 255) & ~(size_t)255;
        return p;
    };
    const size_t SL = (size_t)TB_ * 8192;   // 10.5M
    uint8_t* hsT   = (uint8_t*)alloc(4 * SL);  // [slab*16+n][2048]; overlays qkv spikes
    uint8_t* qsb   = hsT;                      // scan-layout spikes (dead before hsT written)
    uint8_t* ksb   = hsT + SL;
    uint8_t* vsb   = hsT + 2 * SL;
    uint8_t* y1T   = hsT + 3 * SL;             // T-layout spikes (dead before hsT written)
    uint8_t* sproj = (uint8_t*)alloc(SL);
    short* Ah_qkv = (short*)alloc((size_t)1536 * 512 * 2);
    short* Al_qkv = (short*)alloc((size_t)1536 * 512 * 2);
    short* Ah_p   = (short*)alloc((size_t)512 * 512 * 2);
    short* Al_p   = (short*)alloc((size_t)512 * 512 * 2);
    short* Ah_1   = (short*)alloc((size_t)2048 * 512 * 2);
    short* Al_1   = (short*)alloc((size_t)2048 * 512 * 2);
    short* Ah_2   = (short*)alloc((size_t)512 * 2048 * 2);
    short* Al_2   = (short*)alloc((size_t)512 * 2048 * 2);
    float* bs_qkv = (float*)alloc(1536 * 4);
    float* bs_p   = (float*)alloc(512 * 4);
    float* bs_1   = (float*)alloc(2048 * 4);
    float* bs_2   = (float*)alloc(512 * 4);
    // total ~65 MB

    // --- prep: fold BN, split bf16 hi/lo, [m][K] ---
    fold2<<<1024, 256, 0, stream>>>(Wq, bnq, nullptr, 512, 512, 0,    Ah_qkv, Al_qkv, bs_qkv);
    fold2<<<1024, 256, 0, stream>>>(Wk, bnk, nullptr, 512, 512, 512,  Ah_qkv, Al_qkv, bs_qkv);
    fold2<<<1024, 256, 0, stream>>>(Wv, bnv, nullptr, 512, 512, 1024, Ah_qkv, Al_qkv, bs_qkv);
    fold2<<<1024, 256, 0, stream>>>(Wp, bnpj, nullptr, 512, 512, 0,   Ah_p, Al_p, bs_p);
    fold2<<<4096, 256, 0, stream>>>(W1, bn1, b1, 2048, 512, 0,        Ah_1, Al_1, bs_1);
    fold2<<<4096, 256, 0, stream>>>(W2, bn2, b2, 512, 2048, 0,        Ah_2, Al_2, bs_2);

    // --- SSA ---
    gemm_mfma<4, BS_XF32, EP_QKV><<<dim3(6, B_), 256, 0, stream>>>(
        Ah_qkv, Al_qkv, bs_qkv, x, nullptr, qsb, ksb, vsb,
        nullptr, nullptr, nullptr, 512);
    scan_kernel<<<B_ * H_, 64, 0, stream>>>(qsb, ksb, vsb, tiw, tib, y1T);
    gemm_mfma<2, BS_U8T, EP_U8><<<dim3(4, B_), 256, 0, stream>>>(
        Ah_p, Al_p, bs_p, nullptr, y1T, sproj, nullptr, nullptr,
        nullptr, nullptr, nullptr, 512);

    // --- MLP ---  (x2 = x + sproj formed on the fly in staging)
    gemm_mfma<4, BS_XADD, EP_HS><<<dim3(8, B_), 256, 0, stream>>>(
        Ah_1, Al_1, bs_1, x, nullptr, hsT, nullptr, nullptr,
        nullptr, nullptr, sproj, 512);
    gemm_mfma<2, BS_U8T, EP_OUT><<<dim3(4, B_), 256, 0, stream>>>(
        Ah_2, Al_2, bs_2, nullptr, hsT, nullptr, nullptr, nullptr,
        out, x, sproj, 2048);
}